// Round 1
// baseline (3224.173 us; speedup 1.0000x reference)
//
#include <hip/hip_runtime.h>

// LSTMModel: 2-layer LSTM, H=50, B=4096, T=512, D_in=1, then FC(50->1) on last h2.
// Fused persistent kernel: 512 blocks x 256 threads, each block owns 8 batch
// elements for the whole T loop (no cross-block communication).
// Thread r (<200) holds its gate-row weights in registers (156 VGPRs):
//   w0[52]  = W_hh0[r][0..49] zero-padded
//   w1[104] = [W_ih1[r][0..49], 0, 0, W_hh1[r][0..49], 0, 0]
// h-state in LDS hcat[b][104] = [h1(50) pad2 | h2(50) pad2]; broadcast float4 reads.
// Gates route through LDS [b][200] (lane-contiguous both directions -> conflict-free).

#define TT  512
#define BB  4096
#define HH  50
#define NG  200   // 4*H gate rows
#define BPB 8     // batch elements per block
#define KA  52    // padded K for layer-0 recurrent matvec
#define KB  104   // padded K for layer-1 concat matvec

__device__ __forceinline__ float sigf(float v) {
    return 1.0f / (1.0f + __expf(-v));
}
__device__ __forceinline__ float tanh_fast(float v) {
    // tanh(x) = 2*sigmoid(2x) - 1 ; saturates correctly for large |x|
    return 2.0f / (1.0f + __expf(-2.0f * v)) - 1.0f;
}

__global__ __launch_bounds__(256, 2) void lstm_fused(
    const float* __restrict__ x,
    const float* __restrict__ W_ih0, const float* __restrict__ W_hh0,
    const float* __restrict__ b_ih0, const float* __restrict__ b_hh0,
    const float* __restrict__ W_ih1, const float* __restrict__ W_hh1,
    const float* __restrict__ b_ih1, const float* __restrict__ b_hh1,
    const float* __restrict__ W_fc,  const float* __restrict__ b_fc,
    float* __restrict__ out)
{
    __shared__ __align__(16) float hcat[BPB][KB];   // [b][0..49]=h1, [52..101]=h2
    __shared__ float gates[BPB][NG];
    __shared__ float xs[BPB];

    const int tid = threadIdx.x;
    const int b0  = blockIdx.x * BPB;
    const bool rowActive = (tid < NG);
    const int r = tid;

    // ---- load per-row weights into registers (one-time) ----
    float w0[KA];
    float w1[KB];
    float wih0_r = 0.f, bias0_r = 0.f, bias1_r = 0.f;
    if (rowActive) {
        wih0_r  = W_ih0[r];               // D_in == 1 -> scalar per row
        bias0_r = b_ih0[r] + b_hh0[r];
        bias1_r = b_ih1[r] + b_hh1[r];
#pragma unroll
        for (int j = 0; j < KA; ++j) w0[j] = (j < HH) ? W_hh0[r*HH + j] : 0.f;
#pragma unroll
        for (int j = 0; j < KB; ++j) {
            float v = 0.f;
            if (j < HH)                 v = W_ih1[r*HH + j];
            else if (j >= 52 && j < 52+HH) v = W_hh1[r*HH + (j - 52)];
            w1[j] = v;
        }
    } else {
#pragma unroll
        for (int j = 0; j < KA; ++j) w0[j] = 0.f;
#pragma unroll
        for (int j = 0; j < KB; ++j) w1[j] = 0.f;
    }

    // ---- update-phase thread mapping: (unit uu, batch-quarter bq) ----
    const int  uu  = tid & 63;
    const int  bq  = tid >> 6;          // 0..3 -> batches {2bq, 2bq+1}
    const bool uAct = (uu < HH);
    float c0[2] = {0.f, 0.f};
    float c2[2] = {0.f, 0.f};

    // ---- init LDS state ----
    for (int i = tid; i < BPB*KB; i += 256) ((float*)hcat)[i] = 0.f;
    if (tid < BPB) xs[tid] = x[(size_t)(b0 + tid) * TT];   // x[b][t=0]
    __syncthreads();

    for (int t = 0; t < TT; ++t) {
        // ---------- phase A: layer-0 gates ----------
        if (rowActive) {
            float a[BPB];
#pragma unroll
            for (int b = 0; b < BPB; ++b) a[b] = fmaf(xs[b], wih0_r, bias0_r);
#pragma unroll
            for (int jb = 0; jb < KA/4; ++jb) {
#pragma unroll
                for (int b = 0; b < BPB; ++b) {
                    float4 h4 = *((const float4*)&hcat[b][jb*4]);  // broadcast read
                    a[b] = fmaf(w0[jb*4+0], h4.x, a[b]);
                    a[b] = fmaf(w0[jb*4+1], h4.y, a[b]);
                    a[b] = fmaf(w0[jb*4+2], h4.z, a[b]);
                    a[b] = fmaf(w0[jb*4+3], h4.w, a[b]);
                }
            }
#pragma unroll
            for (int b = 0; b < BPB; ++b) gates[b][r] = a[b];
        }
        __syncthreads();   // gates0 ready; all reads of old h1 done

        // ---------- update 0: c0/h1 ----------
        if (uAct) {
#pragma unroll
            for (int k = 0; k < 2; ++k) {
                const int b = 2*bq + k;
                const float gi = gates[b][uu];
                const float gf = gates[b][HH   + uu];
                const float gg = gates[b][2*HH + uu];
                const float go = gates[b][3*HH + uu];
                const float c  = fmaf(sigf(gf), c0[k], sigf(gi) * tanh_fast(gg));
                c0[k] = c;
                hcat[b][uu] = sigf(go) * tanh_fast(c);   // h1 new
            }
        }
        // stage x[:, t+1] with otherwise-idle lanes (uu=56..63, bq=3)
        if (tid >= 248 && (t + 1) < TT)
            xs[tid - 248] = x[(size_t)(b0 + tid - 248) * TT + (t + 1)];
        __syncthreads();   // h1 new visible

        // ---------- phase B: layer-1 gates (K = [h1 | h2]) ----------
        if (rowActive) {
            float a[BPB];
#pragma unroll
            for (int b = 0; b < BPB; ++b) a[b] = bias1_r;
#pragma unroll
            for (int jb = 0; jb < KB/4; ++jb) {
#pragma unroll
                for (int b = 0; b < BPB; ++b) {
                    float4 h4 = *((const float4*)&hcat[b][jb*4]);  // broadcast read
                    a[b] = fmaf(w1[jb*4+0], h4.x, a[b]);
                    a[b] = fmaf(w1[jb*4+1], h4.y, a[b]);
                    a[b] = fmaf(w1[jb*4+2], h4.z, a[b]);
                    a[b] = fmaf(w1[jb*4+3], h4.w, a[b]);
                }
            }
#pragma unroll
            for (int b = 0; b < BPB; ++b) gates[b][r] = a[b];
        }
        __syncthreads();   // gates1 ready; all reads of old h2 done

        // ---------- update 1: c2/h2 ----------
        if (uAct) {
#pragma unroll
            for (int k = 0; k < 2; ++k) {
                const int b = 2*bq + k;
                const float gi = gates[b][uu];
                const float gf = gates[b][HH   + uu];
                const float gg = gates[b][2*HH + uu];
                const float go = gates[b][3*HH + uu];
                const float c  = fmaf(sigf(gf), c2[k], sigf(gi) * tanh_fast(gg));
                c2[k] = c;
                hcat[b][52 + uu] = sigf(go) * tanh_fast(c);  // h2 new
            }
        }
        __syncthreads();   // h2 new visible; gates free for next phase A
    }

    // ---------- FC epilogue: out[b] = h2_last . W_fc + b_fc ----------
    if (tid < BPB) {
        float acc = b_fc[0];
#pragma unroll
        for (int u = 0; u < HH; ++u) acc = fmaf(hcat[tid][52 + u], W_fc[u], acc);
        out[b0 + tid] = acc;
    }
}

extern "C" void kernel_launch(void* const* d_in, const int* in_sizes, int n_in,
                              void* d_out, int out_size, void* d_ws, size_t ws_size,
                              hipStream_t stream) {
    const float* x     = (const float*)d_in[0];
    const float* W_ih0 = (const float*)d_in[1];
    const float* W_hh0 = (const float*)d_in[2];
    const float* b_ih0 = (const float*)d_in[3];
    const float* b_hh0 = (const float*)d_in[4];
    const float* W_ih1 = (const float*)d_in[5];
    const float* W_hh1 = (const float*)d_in[6];
    const float* b_ih1 = (const float*)d_in[7];
    const float* b_hh1 = (const float*)d_in[8];
    const float* W_fc  = (const float*)d_in[9];
    const float* b_fc  = (const float*)d_in[10];
    float* out = (float*)d_out;

    dim3 grid(BB / BPB);   // 512 blocks
    dim3 block(256);
    lstm_fused<<<grid, block, 0, stream>>>(x, W_ih0, W_hh0, b_ih0, b_hh0,
                                           W_ih1, W_hh1, b_ih1, b_hh1,
                                           W_fc, b_fc, out);
}